// Round 1
// 249.298 us; speedup vs baseline: 1.0504x; 1.0504x over previous
//
#include <hip/hip_runtime.h>

#define B_  4
#define S_  2048
#define D_  1024
#define N_  (B_*S_)
#define SCALE 0.03125f
#define NEGINF (-3.0e38f)

typedef unsigned short u16;
typedef __attribute__((ext_vector_type(8))) short short8;
typedef __attribute__((ext_vector_type(4))) float floatx4;

__device__ __forceinline__ u16 f2bf(float f) {           // RNE float->bf16
    unsigned int u = __float_as_uint(f);
    u += 0x7FFFu + ((u >> 16) & 1u);
    return (u16)(u >> 16);
}
__device__ __forceinline__ float bf2f(u16 h) {
    return __uint_as_float((unsigned int)h << 16);
}

__device__ __forceinline__ void gl_lds16(const void* g, void* l) {
    __builtin_amdgcn_global_load_lds(
        (const __attribute__((address_space(1))) unsigned int*)g,
        (__attribute__((address_space(3))) unsigned int*)l, 16, 0, 0);
}

// ---------------- fused casts ----------------
// blocks [0,4096): x cast. [4096,4608): Wq plain. [4608,5120): Wk plain.
// [5120,6144): Wv transposed 32x32 tiles -> Wvt[e][d].
__global__ __launch_bounds__(256) void cast_fused(const float* __restrict__ x,
                                                  const float* __restrict__ Wq, const float* __restrict__ Wk,
                                                  const float* __restrict__ Wv,
                                                  u16* __restrict__ xb, u16* __restrict__ Wqb,
                                                  u16* __restrict__ Wkb, u16* __restrict__ Wvt) {
    __shared__ float t[32][33];
    const int blk = blockIdx.x;
    if (blk < 5120) {
        const float* src; u16* dst; size_t i;
        if (blk < 4096)      { src = x;  dst = xb;  i = (size_t)blk * 2048; }
        else if (blk < 4608) { src = Wq; dst = Wqb; i = (size_t)(blk - 4096) * 2048; }
        else                 { src = Wk; dst = Wkb; i = (size_t)(blk - 4608) * 2048; }
        i += (size_t)threadIdx.x * 8;
        float4 a = *(const float4*)&src[i];
        float4 b = *(const float4*)&src[i + 4];
        short8 o;
        o[0]=f2bf(a.x); o[1]=f2bf(a.y); o[2]=f2bf(a.z); o[3]=f2bf(a.w);
        o[4]=f2bf(b.x); o[5]=f2bf(b.y); o[6]=f2bf(b.z); o[7]=f2bf(b.w);
        *(short8*)&dst[i] = o;
    } else {
        const int tb = blk - 5120;                 // 0..1023
        const int c = threadIdx.x & 31, r0 = threadIdx.x >> 5;
        const int i0 = (tb >> 5) * 32, j0 = (tb & 31) * 32;
#pragma unroll
        for (int rr = 0; rr < 4; ++rr)
            t[r0 + rr * 8][c] = Wv[(size_t)(i0 + r0 + rr * 8) * D_ + j0 + c];
        __syncthreads();
#pragma unroll
        for (int rr = 0; rr < 4; ++rr)
            Wvt[(size_t)(j0 + r0 + rr * 8) * D_ + i0 + c] = f2bf(t[c][r0 + rr * 8]);
    }
}

// ---------------- MFMA 16x16x32 NT-GEMM core, 2-deep pipelined (T3/T4/T5) ----------------
// C[128x128] = A[128xK] * B[128xK]^T.  LDS tiles [row][64] double-buffered,
// 8-elem-group XOR swizzle on the GLOBAL side (LDS dest lane*16-contiguous).
// Pipeline: stage(t+1) issued BEFORE compute(t); counted s_waitcnt vmcnt(8)
// (never 0 in-loop) keeps next tile's 8 loads in flight across raw s_barrier.
__device__ __forceinline__ void mfma_nt_loop(const u16* __restrict__ A, int lda,
                                             const u16* __restrict__ Bp, int ldb,
                                             int m0, int n0, int kext,
                                             u16* As, u16* Bs, floatx4 acc[4][4])
{
    const int tid  = threadIdx.x;
    const int lane = tid & 63;
    const int lr   = lane & 15, quad = lane >> 4;
    const int wm   = ((tid >> 6) & 1) * 64, wn = (tid >> 7) * 64;
    const int e    = tid * 8;
    const int nt   = kext >> 6;

    // stage K-tile starting at k0 into buffer half (0/1): 8 gl_lds / thread
    auto stage = [&](int k0, int half) {
        u16* Ad = As + half * 8192;
        u16* Bd = Bs + half * 8192;
#pragma unroll
        for (int it = 0; it < 4; ++it) {
            int idx = it * 2048 + e;
            int row = idx >> 6;
            int cg  = (idx & 63) >> 3;
            int gc  = (cg ^ (row & 7)) << 3;   // swizzled global k-offset
            gl_lds16(&A [(size_t)(m0 + row) * lda + k0 + gc], &Ad[idx]);
            gl_lds16(&Bp[(size_t)(n0 + row) * ldb + k0 + gc], &Bd[idx]);
        }
    };

    stage(0, 0);
    int cur = 0;
    for (int t = 0; t < nt; ++t) {
        if (t + 1 < nt) {
            stage((t + 1) << 6, cur ^ 1);                  // 8 more loads in flight
            asm volatile("s_waitcnt vmcnt(8)" ::: "memory"); // tile t's 8 done; t+1 stays in flight
        } else {
            asm volatile("s_waitcnt vmcnt(0)" ::: "memory"); // drain last tile
        }
        __builtin_amdgcn_s_barrier();                      // buf[cur] ready for all waves

        const u16* Asb = As + cur * 8192;
        const u16* Bsb = Bs + cur * 8192;
#pragma unroll
        for (int kk = 0; kk < 2; ++kk) {
            short8 af[4], bf[4];
            const int kg = kk * 4 + quad;
#pragma unroll
            for (int i = 0; i < 4; ++i) {
                int am = wm + i * 16 + lr;
                af[i] = *(const short8*)&Asb[am * 64 + ((kg ^ (am & 7)) << 3)];
                int bn = wn + i * 16 + lr;
                bf[i] = *(const short8*)&Bsb[bn * 64 + ((kg ^ (bn & 7)) << 3)];
            }
            __builtin_amdgcn_s_setprio(1);
#pragma unroll
            for (int i = 0; i < 4; ++i)
#pragma unroll
                for (int j = 0; j < 4; ++j)
                    acc[i][j] = __builtin_amdgcn_mfma_f32_16x16x32_bf16(af[i], bf[j], acc[i][j], 0, 0, 0);
            __builtin_amdgcn_s_setprio(0);
        }
        asm volatile("s_waitcnt lgkmcnt(0)" ::: "memory"); // all ds_reads of buf[cur] retired
        __builtin_amdgcn_s_barrier();                      // safe to overwrite buf[cur] next iter
        cur ^= 1;
    }
}

// C/D layout (verified): col = lane&15, row = (lane>>4)*4 + reg
#define EPI_VARS                                              \
    const int lane = threadIdx.x & 63;                        \
    const int lr = lane & 15, quad = lane >> 4;               \
    const int wm = ((threadIdx.x >> 6) & 1) * 64, wn = (threadIdx.x >> 7) * 64;

// ---------------- K1: Mt = Wk *NT* Wq ----------------
__global__ __launch_bounds__(256) void mt_mfma(const u16* __restrict__ Wkb, const u16* __restrict__ Wqb,
                                               u16* __restrict__ Mt)
{
    __shared__ u16 As[16384], Bs[16384];
    const int m0 = blockIdx.y * 128, n0 = blockIdx.x * 128;
    floatx4 acc[4][4];
#pragma unroll
    for (int i = 0; i < 4; ++i)
#pragma unroll
        for (int j = 0; j < 4; ++j) acc[i][j] = (floatx4){0.f, 0.f, 0.f, 0.f};
    mfma_nt_loop(Wkb, D_, Wqb, D_, m0, n0, D_, As, Bs, acc);

    EPI_VARS
#pragma unroll
    for (int i = 0; i < 4; ++i)
#pragma unroll
        for (int j = 0; j < 4; ++j)
#pragma unroll
            for (int r = 0; r < 4; ++r)
                Mt[(size_t)(m0 + wm + i * 16 + quad * 4 + r) * D_ + n0 + wn + j * 16 + lr] = f2bf(acc[i][j][r]);
}

// ---------------- K2+K3 merged: y = x*NT*Mt  and  Vt = (x*NT*Wvt)^T ----------------
// id<512: Y tile (m=id>>3 of 64, n=id&7).  id>=512: V tile (b=v>>7, m=(v>>3)&15, n=v&7).
__global__ __launch_bounds__(256) void yv_mfma(const u16* __restrict__ xb, const u16* __restrict__ Mt,
                                               const u16* __restrict__ Wvt,
                                               u16* __restrict__ Y, u16* __restrict__ Vt)
{
    __shared__ u16 As[16384], Bs[16384];
    const int id = blockIdx.x;
    floatx4 acc[4][4];
#pragma unroll
    for (int i = 0; i < 4; ++i)
#pragma unroll
        for (int j = 0; j < 4; ++j) acc[i][j] = (floatx4){0.f, 0.f, 0.f, 0.f};

    if (id < 512) {
        const int m0 = (id >> 3) * 128, n0 = (id & 7) * 128;
        mfma_nt_loop(xb, D_, Mt, D_, m0, n0, D_, As, Bs, acc);
        EPI_VARS
#pragma unroll
        for (int i = 0; i < 4; ++i)
#pragma unroll
            for (int j = 0; j < 4; ++j)
#pragma unroll
                for (int r = 0; r < 4; ++r)
                    Y[(size_t)(m0 + wm + i * 16 + quad * 4 + r) * D_ + n0 + wn + j * 16 + lr] = f2bf(acc[i][j][r]);
    } else {
        const int v = id - 512;
        const int b = v >> 7;
        const int mloc = ((v >> 3) & 15) * 128;
        const int n0 = (v & 7) * 128;
        const int m0 = b * S_ + mloc;
        u16* Vb = Vt + (size_t)b * D_ * S_;
        mfma_nt_loop(xb, D_, Wvt, D_, m0, n0, D_, As, Bs, acc);
        EPI_VARS
#pragma unroll
        for (int i = 0; i < 4; ++i)
#pragma unroll
            for (int j = 0; j < 4; ++j) {
                const int ee = n0 + wn + j * 16 + lr;
                const int s4 = mloc + wm + i * 16 + quad * 4;   // 4 contiguous s
                ushort4 o;
                o.x = f2bf(acc[i][j][0]); o.y = f2bf(acc[i][j][1]);
                o.z = f2bf(acc[i][j][2]); o.w = f2bf(acc[i][j][3]);
                *(ushort4*)&Vb[(size_t)ee * S_ + s4] = o;       // 8B aligned (s4 % 4 == 0)
            }
    }
}

// ---------------- K4: Sc = bf16(scale * Y x^T), packed causal triangle ----------------
__global__ __launch_bounds__(256) void scores_mfma(const u16* __restrict__ Y, const u16* __restrict__ xb,
                                                   u16* __restrict__ Sc)
{
    const int t = blockIdx.x, b = blockIdx.z;
    int qt = (int)((sqrtf(8.0f * t + 1.0f) - 1.0f) * 0.5f);
    while ((qt + 1) * (qt + 2) / 2 <= t) ++qt;
    while (qt * (qt + 1) / 2 > t) --qt;
    const int kt = t - qt * (qt + 1) / 2;

    __shared__ u16 As[16384], Bs[16384];
    const u16* A  = Y  + (size_t)b * S_ * D_;
    const u16* Bp = xb + (size_t)b * S_ * D_;
    u16* Sb = Sc + (size_t)b * S_ * S_;
    const int m0 = qt * 128, n0 = kt * 128;
    floatx4 acc[4][4];
#pragma unroll
    for (int i = 0; i < 4; ++i)
#pragma unroll
        for (int j = 0; j < 4; ++j) acc[i][j] = (floatx4){0.f, 0.f, 0.f, 0.f};
    mfma_nt_loop(A, D_, Bp, D_, m0, n0, D_, As, Bs, acc);

    EPI_VARS
#pragma unroll
    for (int i = 0; i < 4; ++i)
#pragma unroll
        for (int r = 0; r < 4; ++r) {
            const int grow = m0 + wm + i * 16 + quad * 4 + r;
#pragma unroll
            for (int j = 0; j < 4; ++j) {
                const int gcol = n0 + wn + j * 16 + lr;
                const float v = (gcol <= grow) ? acc[i][j][r] * SCALE : NEGINF;
                Sb[(size_t)grow * S_ + gcol] = f2bf(v);
            }
        }
}

// ---------------- K5: row softmax, bf16 in -> bf16 P out (register-resident) ----------------
__global__ __launch_bounds__(256) void softmax_k(const u16* __restrict__ Sc, u16* __restrict__ P)
{
    const int row = blockIdx.x;
    const int b = row >> 11, q = row & (S_ - 1);
    const int L = ((q >> 7) + 1) << 7;           // 128-granular causal span
    const u16* rp = Sc + ((size_t)b * S_ + q) * S_;
    u16* pp = P + ((size_t)b * S_ + q) * S_;
    __shared__ float red[4];
    __shared__ float bc;
    const int tid = threadIdx.x;
    const int i = tid << 3;
    const bool act = i < L;

    float f[8];
    float lmax = -3.4e38f;
    if (act) {
        short8 v = *(const short8*)&rp[i];
#pragma unroll
        for (int k = 0; k < 8; ++k) { f[k] = bf2f((u16)v[k]); lmax = fmaxf(lmax, f[k]); }
    }
    for (int off = 32; off; off >>= 1) lmax = fmaxf(lmax, __shfl_down(lmax, off, 64));
    if ((tid & 63) == 0) red[tid >> 6] = lmax;
    __syncthreads();
    if (tid == 0) bc = fmaxf(fmaxf(red[0], red[1]), fmaxf(red[2], red[3]));
    __syncthreads();
    const float m = bc;

    float lsum = 0.f;
    if (act) {
#pragma unroll
        for (int k = 0; k < 8; ++k) { f[k] = __expf(f[k] - m); lsum += f[k]; }
    }
    for (int off = 32; off; off >>= 1) lsum += __shfl_down(lsum, off, 64);
    if ((tid & 63) == 0) red[tid >> 6] = lsum;
    __syncthreads();
    if (tid == 0) bc = red[0] + red[1] + red[2] + red[3];
    __syncthreads();
    const float inv = 1.0f / bc;

    if (act) {
        short8 o;
#pragma unroll
        for (int k = 0; k < 8; ++k) o[k] = (short)f2bf(f[k] * inv);
        *(short8*)&pp[i] = o;
    }
}

// ---------------- K6: O = P Vt^T (causal K-extent), fp32 out ----------------
__global__ __launch_bounds__(256) void pv_mfma(const u16* __restrict__ P, const u16* __restrict__ Vt,
                                               float* __restrict__ O)
{
    const int et = blockIdx.x, qt = blockIdx.y, b = blockIdx.z;
    __shared__ u16 As[16384], Bs[16384];
    const u16* A  = P  + (size_t)b * S_ * S_;
    const u16* Bp = Vt + (size_t)b * D_ * S_;
    const int m0 = qt * 128, n0 = et * 128;
    const int kext = (qt + 1) * 128;
    floatx4 acc[4][4];
#pragma unroll
    for (int i = 0; i < 4; ++i)
#pragma unroll
        for (int j = 0; j < 4; ++j) acc[i][j] = (floatx4){0.f, 0.f, 0.f, 0.f};
    mfma_nt_loop(A, S_, Bp, S_, m0, n0, kext, As, Bs, acc);

    EPI_VARS
#pragma unroll
    for (int i = 0; i < 4; ++i)
#pragma unroll
        for (int r = 0; r < 4; ++r) {
            const int grow = m0 + wm + i * 16 + quad * 4 + r;
#pragma unroll
            for (int j = 0; j < 4; ++j)
                O[((size_t)b * S_ + grow) * D_ + n0 + wn + j * 16 + lr] = acc[i][j][r];
        }
}

extern "C" void kernel_launch(void* const* d_in, const int* in_sizes, int n_in,
                              void* d_out, int out_size, void* d_ws, size_t ws_size,
                              hipStream_t stream) {
    const float* x  = (const float*)d_in[0];
    const float* Wq = (const float*)d_in[1];
    const float* Wk = (const float*)d_in[2];
    const float* Wv = (const float*)d_in[3];
    float* out = (float*)d_out;
    char* w = (char*)d_ws;

    // workspace layout (bytes)
    u16* xb  = (u16*)(w);                    // 16.8 MB
    u16* Wqb = (u16*)(w + 16777216);         //  2 MB
    u16* Wkb = (u16*)(w + 18874368);         //  2 MB
    u16* Wvt = (u16*)(w + 20971520);         //  2 MB
    u16* Mt  = (u16*)(w + 23068672);         //  2 MB
    u16* Y   = (u16*)(w + 25165824);         // 16.8 MB
    u16* Vt  = (u16*)(w + 41943040);         // 16.8 MB
    u16* Sc  = (u16*)(w + 58720256);         // 33.5 MB
    u16* P   = (u16*)(w + 92274688);         // 33.5 MB

    cast_fused <<<dim3(6144),        256, 0, stream>>>(x, Wq, Wk, Wv, xb, Wqb, Wkb, Wvt);
    mt_mfma    <<<dim3(8, 8),        256, 0, stream>>>(Wkb, Wqb, Mt);
    yv_mfma    <<<dim3(1024),        256, 0, stream>>>(xb, Mt, Wvt, Y, Vt);
    scores_mfma<<<dim3(136, 1, B_),  256, 0, stream>>>(Y, xb, Sc);
    softmax_k  <<<dim3(N_),          256, 0, stream>>>(Sc, P);
    pv_mfma    <<<dim3(8, 16, B_),   256, 0, stream>>>(P, Vt, out);
}

// Round 2
// 233.925 us; speedup vs baseline: 1.1194x; 1.0657x over previous
//
#include <hip/hip_runtime.h>

#define B_  4
#define S_  2048
#define D_  1024
#define N_  (B_*S_)
#define SCALE 0.03125f
#define NEGINF (-3.0e38f)

typedef unsigned short u16;
typedef __attribute__((ext_vector_type(8))) short short8;
typedef __attribute__((ext_vector_type(4))) float floatx4;

__device__ __forceinline__ u16 f2bf(float f) {           // RNE float->bf16
    unsigned int u = __float_as_uint(f);
    u += 0x7FFFu + ((u >> 16) & 1u);
    return (u16)(u >> 16);
}
__device__ __forceinline__ float bf2f(u16 h) {
    return __uint_as_float((unsigned int)h << 16);
}

__device__ __forceinline__ void gl_lds16(const void* g, void* l) {
    __builtin_amdgcn_global_load_lds(
        (const __attribute__((address_space(1))) unsigned int*)g,
        (__attribute__((address_space(3))) unsigned int*)l, 16, 0, 0);
}

// bijective chunked XCD swizzle (nwg % 8 == 0): XCD x owns logical ids [x*nwg/8, ...)
__device__ __forceinline__ int xcd_chunk(int bid, int nwg) {
    return (bid & 7) * (nwg >> 3) + (bid >> 3);
}

// ---------------- fused casts ----------------
__global__ __launch_bounds__(256) void cast_fused(const float* __restrict__ x,
                                                  const float* __restrict__ Wq, const float* __restrict__ Wk,
                                                  const float* __restrict__ Wv,
                                                  u16* __restrict__ xb, u16* __restrict__ Wqb,
                                                  u16* __restrict__ Wkb, u16* __restrict__ Wvt) {
    __shared__ float t[32][33];
    const int blk = blockIdx.x;
    if (blk < 5120) {
        const float* src; u16* dst; size_t i;
        if (blk < 4096)      { src = x;  dst = xb;  i = (size_t)blk * 2048; }
        else if (blk < 4608) { src = Wq; dst = Wqb; i = (size_t)(blk - 4096) * 2048; }
        else                 { src = Wk; dst = Wkb; i = (size_t)(blk - 4608) * 2048; }
        i += (size_t)threadIdx.x * 8;
        float4 a = *(const float4*)&src[i];
        float4 b = *(const float4*)&src[i + 4];
        short8 o;
        o[0]=f2bf(a.x); o[1]=f2bf(a.y); o[2]=f2bf(a.z); o[3]=f2bf(a.w);
        o[4]=f2bf(b.x); o[5]=f2bf(b.y); o[6]=f2bf(b.z); o[7]=f2bf(b.w);
        *(short8*)&dst[i] = o;
    } else {
        const int tb = blk - 5120;                 // 0..1023
        const int c = threadIdx.x & 31, r0 = threadIdx.x >> 5;
        const int i0 = (tb >> 5) * 32, j0 = (tb & 31) * 32;
#pragma unroll
        for (int rr = 0; rr < 4; ++rr)
            t[r0 + rr * 8][c] = Wv[(size_t)(i0 + r0 + rr * 8) * D_ + j0 + c];
        __syncthreads();
#pragma unroll
        for (int rr = 0; rr < 4; ++rr)
            Wvt[(size_t)(j0 + r0 + rr * 8) * D_ + i0 + c] = f2bf(t[c][r0 + rr * 8]);
    }
}

// ================= 128x128 core (round-1 verified, kept for mt/pv) =================
__device__ __forceinline__ void mfma_nt_loop(const u16* __restrict__ A, int lda,
                                             const u16* __restrict__ Bp, int ldb,
                                             int m0, int n0, int kext,
                                             u16* As, u16* Bs, floatx4 acc[4][4])
{
    const int tid  = threadIdx.x;
    const int lane = tid & 63;
    const int lr   = lane & 15, quad = lane >> 4;
    const int wm   = ((tid >> 6) & 1) * 64, wn = (tid >> 7) * 64;
    const int e    = tid * 8;
    const int nt   = kext >> 6;

    auto stage = [&](int k0, int half) {
        u16* Ad = As + half * 8192;
        u16* Bd = Bs + half * 8192;
#pragma unroll
        for (int it = 0; it < 4; ++it) {
            int idx = it * 2048 + e;
            int row = idx >> 6;
            int cg  = (idx & 63) >> 3;
            int gc  = (cg ^ (row & 7)) << 3;
            gl_lds16(&A [(size_t)(m0 + row) * lda + k0 + gc], &Ad[idx]);
            gl_lds16(&Bp[(size_t)(n0 + row) * ldb + k0 + gc], &Bd[idx]);
        }
    };

    stage(0, 0);
    int cur = 0;
    for (int t = 0; t < nt; ++t) {
        if (t + 1 < nt) {
            stage((t + 1) << 6, cur ^ 1);
            asm volatile("s_waitcnt vmcnt(8)" ::: "memory");
        } else {
            asm volatile("s_waitcnt vmcnt(0)" ::: "memory");
        }
        __builtin_amdgcn_s_barrier();

        const u16* Asb = As + cur * 8192;
        const u16* Bsb = Bs + cur * 8192;
#pragma unroll
        for (int kk = 0; kk < 2; ++kk) {
            short8 af[4], bf[4];
            const int kg = kk * 4 + quad;
#pragma unroll
            for (int i = 0; i < 4; ++i) {
                int am = wm + i * 16 + lr;
                af[i] = *(const short8*)&Asb[am * 64 + ((kg ^ (am & 7)) << 3)];
                int bn = wn + i * 16 + lr;
                bf[i] = *(const short8*)&Bsb[bn * 64 + ((kg ^ (bn & 7)) << 3)];
            }
            __builtin_amdgcn_s_setprio(1);
#pragma unroll
            for (int i = 0; i < 4; ++i)
#pragma unroll
                for (int j = 0; j < 4; ++j)
                    acc[i][j] = __builtin_amdgcn_mfma_f32_16x16x32_bf16(af[i], bf[j], acc[i][j], 0, 0, 0);
            __builtin_amdgcn_s_setprio(0);
        }
        asm volatile("s_waitcnt lgkmcnt(0)" ::: "memory");
        __builtin_amdgcn_s_barrier();
        cur ^= 1;
    }
}

#define EPI_VARS                                              \
    const int lane = threadIdx.x & 63;                        \
    const int lr = lane & 15, quad = lane >> 4;               \
    const int wm = ((threadIdx.x >> 6) & 1) * 64, wn = (threadIdx.x >> 7) * 64;

// ================= 256x256 core: 8 waves (2M x 4N), BK=64, 4-phase, counted vmcnt ===========
// Per wave: 128x64 output = acc[8][4]. Per tile per wave: 24 ds_read_b128 (B reg-resident),
// 64 MFMA in 4 clusters of 16. Staging: 8 gl_lds/thread/tile spread 2/phase into the
// opposite buffer; vmcnt(2) once per tile waits exactly the current tile's loads.
__device__ __forceinline__ void mfma_nt_256(const u16* __restrict__ A, int lda,
                                            const u16* __restrict__ Bp, int ldb,
                                            int m0, int n0, int kext,
                                            u16* As, u16* Bs, floatx4 acc[8][4])
{
    const int tid  = threadIdx.x;            // 0..511
    const int lane = tid & 63;
    const int lr   = lane & 15, quad = lane >> 4;
    const int wid  = tid >> 6;               // 0..7
    const int wr   = wid >> 2;               // 0..1  (M half)
    const int wc   = wid & 3;                // 0..3  (N quarter)
    const int nt   = kext >> 6;

    // issue chunks c0, c0+1 of tile t (c<4: A, else B). 2 gl_lds / thread.
    auto stage2 = [&](int t, int c0) {
        const int k0 = t << 6;
        u16* Ad = As + (t & 1) * 16384;
        u16* Bd = Bs + (t & 1) * 16384;
#pragma unroll
        for (int c = c0; c < c0 + 2; ++c) {
            int idx = (c & 3) * 4096 + tid * 8;
            int row = idx >> 6;
            int cg  = (idx & 63) >> 3;
            int gc  = (cg ^ (row & 7)) << 3;
            if (c < 4) gl_lds16(&A [(size_t)(m0 + row) * lda + k0 + gc], &Ad[idx]);
            else       gl_lds16(&Bp[(size_t)(n0 + row) * ldb + k0 + gc], &Bd[idx]);
        }
    };

    // prologue: all of tile 0
    stage2(0, 0); stage2(0, 2); stage2(0, 4); stage2(0, 6);

    for (int t = 0; t < nt; ++t) {
        const u16* Asb = As + (t & 1) * 16384;
        const u16* Bsb = Bs + (t & 1) * 16384;
        const bool pf = (t + 1 < nt);

        short8 af[4][2], bfA[2][2], bfB[2][2];

#pragma unroll
        for (int p = 0; p < 4; ++p) {
            // staging into the opposite buffer (freed at end of tile t-1)
            if (p == 0) {
                if (pf) { stage2(t + 1, 0);
                          asm volatile("s_waitcnt vmcnt(2)" ::: "memory"); }
                else      asm volatile("s_waitcnt vmcnt(0)" ::: "memory");
                __builtin_amdgcn_s_barrier();          // buf[t&1] ready for all waves
            } else if (pf) {
                stage2(t + 1, p * 2);
            }

            // per-phase fragment loads (static pattern: 12 / 4 / 8 / 0 reads)
            if (p == 0) {
#pragma unroll
                for (int i = 0; i < 4; ++i) {
                    int am = wr * 128 + i * 16 + lr;
#pragma unroll
                    for (int kk = 0; kk < 2; ++kk)
                        af[i][kk] = *(const short8*)&Asb[am * 64 + (((kk * 4 + quad) ^ (am & 7)) << 3)];
                }
#pragma unroll
                for (int j = 0; j < 2; ++j) {
                    int bn = wc * 64 + j * 16 + lr;
#pragma unroll
                    for (int kk = 0; kk < 2; ++kk)
                        bfA[j][kk] = *(const short8*)&Bsb[bn * 64 + (((kk * 4 + quad) ^ (bn & 7)) << 3)];
                }
            } else if (p == 1) {
#pragma unroll
                for (int j = 0; j < 2; ++j) {
                    int bn = wc * 64 + (j + 2) * 16 + lr;
#pragma unroll
                    for (int kk = 0; kk < 2; ++kk)
                        bfB[j][kk] = *(const short8*)&Bsb[bn * 64 + (((kk * 4 + quad) ^ (bn & 7)) << 3)];
                }
            } else if (p == 2) {
#pragma unroll
                for (int i = 0; i < 4; ++i) {
                    int am = wr * 128 + (i + 4) * 16 + lr;
#pragma unroll
                    for (int kk = 0; kk < 2; ++kk)
                        af[i][kk] = *(const short8*)&Asb[am * 64 + (((kk * 4 + quad) ^ (am & 7)) << 3)];
                }
            }

            // 16-MFMA cluster: quadrant (mh = p>>1, nh = p&1)
            const int mb = (p >> 1) * 4, nb = (p & 1) * 2;
            __builtin_amdgcn_s_setprio(1);
#pragma unroll
            for (int kk = 0; kk < 2; ++kk)
#pragma unroll
                for (int i = 0; i < 4; ++i)
#pragma unroll
                    for (int j = 0; j < 2; ++j)
                        acc[mb + i][nb + j] = __builtin_amdgcn_mfma_f32_16x16x32_bf16(
                            af[i][kk], (p & 1) ? bfB[j][kk] : bfA[j][kk], acc[mb + i][nb + j], 0, 0, 0);
            __builtin_amdgcn_s_setprio(0);
            asm volatile("s_waitcnt lgkmcnt(0)" ::: "memory");
            __builtin_amdgcn_s_barrier();              // end of phase
        }
    }
}

#define EPI256_VARS                                           \
    const int lane = threadIdx.x & 63;                        \
    const int lr = lane & 15, quad = lane >> 4;               \
    const int wr = (threadIdx.x >> 8) & 1, wc = (threadIdx.x >> 6) & 3;

// ---------------- K1: Mt = Wk *NT* Wq (small, 128-core) ----------------
__global__ __launch_bounds__(256) void mt_mfma(const u16* __restrict__ Wkb, const u16* __restrict__ Wqb,
                                               u16* __restrict__ Mt)
{
    __shared__ u16 As[16384], Bs[16384];
    const int m0 = blockIdx.y * 128, n0 = blockIdx.x * 128;
    floatx4 acc[4][4];
#pragma unroll
    for (int i = 0; i < 4; ++i)
#pragma unroll
        for (int j = 0; j < 4; ++j) acc[i][j] = (floatx4){0.f, 0.f, 0.f, 0.f};
    mfma_nt_loop(Wkb, D_, Wqb, D_, m0, n0, D_, As, Bs, acc);

    EPI_VARS
#pragma unroll
    for (int i = 0; i < 4; ++i)
#pragma unroll
        for (int j = 0; j < 4; ++j)
#pragma unroll
            for (int r = 0; r < 4; ++r)
                Mt[(size_t)(m0 + wm + i * 16 + quad * 4 + r) * D_ + n0 + wn + j * 16 + lr] = f2bf(acc[i][j][r]);
}

// ---------------- K2+K3 merged on 256^2 core: 256 blocks = 1/CU ----------------
// lid<128: Y tile (m=lid>>2, n=lid&3). lid>=128: V tile (b, m, n).
__global__ __launch_bounds__(512, 2) void yv_mfma(const u16* __restrict__ xb, const u16* __restrict__ Mt,
                                                  const u16* __restrict__ Wvt,
                                                  u16* __restrict__ Y, u16* __restrict__ Vt)
{
    __shared__ u16 As[32768], Bs[32768];                 // 2 x 32KB each = 128 KiB total
    const int lid = xcd_chunk(blockIdx.x, 256);
    floatx4 acc[8][4];
#pragma unroll
    for (int i = 0; i < 8; ++i)
#pragma unroll
        for (int j = 0; j < 4; ++j) acc[i][j] = (floatx4){0.f, 0.f, 0.f, 0.f};

    if (lid < 128) {
        const int m0 = (lid >> 2) * 256, n0 = (lid & 3) * 256;
        mfma_nt_256(xb, D_, Mt, D_, m0, n0, D_, As, Bs, acc);
        EPI256_VARS
#pragma unroll
        for (int i = 0; i < 8; ++i)
#pragma unroll
            for (int j = 0; j < 4; ++j)
#pragma unroll
                for (int r = 0; r < 4; ++r)
                    Y[(size_t)(m0 + wr * 128 + i * 16 + quad * 4 + r) * D_ + n0 + wc * 64 + j * 16 + lr]
                        = f2bf(acc[i][j][r]);
    } else {
        const int v = lid - 128;
        const int b = v >> 5;
        const int mloc = ((v >> 2) & 7) * 256;
        const int n0 = (v & 3) * 256;
        const int m0 = b * S_ + mloc;
        u16* Vb = Vt + (size_t)b * D_ * S_;
        mfma_nt_256(xb, D_, Wvt, D_, m0, n0, D_, As, Bs, acc);
        EPI256_VARS
#pragma unroll
        for (int i = 0; i < 8; ++i)
#pragma unroll
            for (int j = 0; j < 4; ++j) {
                const int ee = n0 + wc * 64 + j * 16 + lr;
                const int s4 = mloc + wr * 128 + i * 16 + quad * 4;
                ushort4 o;
                o.x = f2bf(acc[i][j][0]); o.y = f2bf(acc[i][j][1]);
                o.z = f2bf(acc[i][j][2]); o.w = f2bf(acc[i][j][3]);
                *(ushort4*)&Vb[(size_t)ee * S_ + s4] = o;
            }
    }
}

// ---------------- K4: Sc = bf16(scale * Y x^T), 256-granular causal triangle ----------------
__global__ __launch_bounds__(512, 2) void scores_mfma(const u16* __restrict__ Y, const u16* __restrict__ xb,
                                                      u16* __restrict__ Sc)
{
    __shared__ u16 As[32768], Bs[32768];
    const int lid = xcd_chunk(blockIdx.x, 144);
    const int b = lid / 36;
    const int t = lid - b * 36;
    int qt = 0;
    while ((qt + 1) * (qt + 2) / 2 <= t) ++qt;
    const int kt = t - qt * (qt + 1) / 2;

    const u16* A  = Y  + (size_t)b * S_ * D_;
    const u16* Bp = xb + (size_t)b * S_ * D_;
    u16* Sb = Sc + (size_t)b * S_ * S_;
    const int m0 = qt * 256, n0 = kt * 256;
    floatx4 acc[8][4];
#pragma unroll
    for (int i = 0; i < 8; ++i)
#pragma unroll
        for (int j = 0; j < 4; ++j) acc[i][j] = (floatx4){0.f, 0.f, 0.f, 0.f};
    mfma_nt_256(A, D_, Bp, D_, m0, n0, D_, As, Bs, acc);

    EPI256_VARS
#pragma unroll
    for (int i = 0; i < 8; ++i)
#pragma unroll
        for (int r = 0; r < 4; ++r) {
            const int grow = m0 + wr * 128 + i * 16 + quad * 4 + r;
#pragma unroll
            for (int j = 0; j < 4; ++j) {
                const int gcol = n0 + wc * 64 + j * 16 + lr;
                const float v = (gcol <= grow) ? acc[i][j][r] * SCALE : NEGINF;
                Sb[(size_t)grow * S_ + gcol] = f2bf(v);
            }
        }
}

// ---------------- K5: row softmax ----------------
__global__ __launch_bounds__(256) void softmax_k(const u16* __restrict__ Sc, u16* __restrict__ P)
{
    const int row = blockIdx.x;
    const int b = row >> 11, q = row & (S_ - 1);
    const int L = ((q >> 7) + 1) << 7;
    const u16* rp = Sc + ((size_t)b * S_ + q) * S_;
    u16* pp = P + ((size_t)b * S_ + q) * S_;
    __shared__ float red[4];
    __shared__ float bc;
    const int tid = threadIdx.x;
    const int i = tid << 3;
    const bool act = i < L;

    float f[8];
    float lmax = -3.4e38f;
    if (act) {
        short8 v = *(const short8*)&rp[i];
#pragma unroll
        for (int k = 0; k < 8; ++k) { f[k] = bf2f((u16)v[k]); lmax = fmaxf(lmax, f[k]); }
    }
    for (int off = 32; off; off >>= 1) lmax = fmaxf(lmax, __shfl_down(lmax, off, 64));
    if ((tid & 63) == 0) red[tid >> 6] = lmax;
    __syncthreads();
    if (tid == 0) bc = fmaxf(fmaxf(red[0], red[1]), fmaxf(red[2], red[3]));
    __syncthreads();
    const float m = bc;

    float lsum = 0.f;
    if (act) {
#pragma unroll
        for (int k = 0; k < 8; ++k) { f[k] = __expf(f[k] - m); lsum += f[k]; }
    }
    for (int off = 32; off; off >>= 1) lsum += __shfl_down(lsum, off, 64);
    if ((tid & 63) == 0) red[tid >> 6] = lsum;
    __syncthreads();
    if (tid == 0) bc = red[0] + red[1] + red[2] + red[3];
    __syncthreads();
    const float inv = 1.0f / bc;

    if (act) {
        short8 o;
#pragma unroll
        for (int k = 0; k < 8; ++k) o[k] = (short)f2bf(f[k] * inv);
        *(short8*)&pp[i] = o;
    }
}

// ---------------- K6: O = P Vt^T (causal K-extent), 128-core, et-major XCD chunks ----------------
__global__ __launch_bounds__(256) void pv_mfma(const u16* __restrict__ P, const u16* __restrict__ Vt,
                                               float* __restrict__ O)
{
    const int lid = xcd_chunk(blockIdx.x, 512);
    const int b  = lid >> 7;
    const int r  = lid & 127;
    const int et = r >> 4, qt = r & 15;       // consecutive lids share et -> Vt panel L2-resident
    __shared__ u16 As[16384], Bs[16384];
    const u16* A  = P  + (size_t)b * S_ * S_;
    const u16* Bp = Vt + (size_t)b * D_ * S_;
    const int m0 = qt * 128, n0 = et * 128;
    const int kext = (qt + 1) * 128;
    floatx4 acc[4][4];
#pragma unroll
    for (int i = 0; i < 4; ++i)
#pragma unroll
        for (int j = 0; j < 4; ++j) acc[i][j] = (floatx4){0.f, 0.f, 0.f, 0.f};
    mfma_nt_loop(A, S_, Bp, S_, m0, n0, kext, As, Bs, acc);

    EPI_VARS
#pragma unroll
    for (int i = 0; i < 4; ++i)
#pragma unroll
        for (int r2 = 0; r2 < 4; ++r2) {
            const int grow = m0 + wm + i * 16 + quad * 4 + r2;
#pragma unroll
            for (int j = 0; j < 4; ++j)
                O[((size_t)b * S_ + grow) * D_ + n0 + wn + j * 16 + lr] = acc[i][j][r2];
        }
}

extern "C" void kernel_launch(void* const* d_in, const int* in_sizes, int n_in,
                              void* d_out, int out_size, void* d_ws, size_t ws_size,
                              hipStream_t stream) {
    const float* x  = (const float*)d_in[0];
    const float* Wq = (const float*)d_in[1];
    const float* Wk = (const float*)d_in[2];
    const float* Wv = (const float*)d_in[3];
    float* out = (float*)d_out;
    char* w = (char*)d_ws;

    u16* xb  = (u16*)(w);                    // 16.8 MB
    u16* Wqb = (u16*)(w + 16777216);         //  2 MB
    u16* Wkb = (u16*)(w + 18874368);         //  2 MB
    u16* Wvt = (u16*)(w + 20971520);         //  2 MB
    u16* Mt  = (u16*)(w + 23068672);         //  2 MB
    u16* Y   = (u16*)(w + 25165824);         // 16.8 MB
    u16* Vt  = (u16*)(w + 41943040);         // 16.8 MB
    u16* Sc  = (u16*)(w + 58720256);         // 33.5 MB
    u16* P   = (u16*)(w + 92274688);         // 33.5 MB

    cast_fused <<<dim3(6144),   256, 0, stream>>>(x, Wq, Wk, Wv, xb, Wqb, Wkb, Wvt);
    mt_mfma    <<<dim3(8, 8),   256, 0, stream>>>(Wkb, Wqb, Mt);
    yv_mfma    <<<dim3(256),    512, 0, stream>>>(xb, Mt, Wvt, Y, Vt);
    scores_mfma<<<dim3(144),    512, 0, stream>>>(Y, xb, Sc);
    softmax_k  <<<dim3(N_),     256, 0, stream>>>(Sc, P);
    pv_mfma    <<<dim3(512),    256, 0, stream>>>(P, Vt, out);
}

// Round 3
// 226.492 us; speedup vs baseline: 1.1561x; 1.0328x over previous
//
#include <hip/hip_runtime.h>

#define B_  4
#define S_  2048
#define D_  1024
#define N_  (B_*S_)
#define SCALE 0.03125f
#define NEGINF (-3.0e38f)

typedef unsigned short u16;
typedef __attribute__((ext_vector_type(8))) short short8;
typedef __attribute__((ext_vector_type(4))) float floatx4;

__device__ __forceinline__ u16 f2bf(float f) {           // RNE float->bf16
    unsigned int u = __float_as_uint(f);
    u += 0x7FFFu + ((u >> 16) & 1u);
    return (u16)(u >> 16);
}
__device__ __forceinline__ float bf2f(u16 h) {
    return __uint_as_float((unsigned int)h << 16);
}

__device__ __forceinline__ void gl_lds16(const void* g, void* l) {
    __builtin_amdgcn_global_load_lds(
        (const __attribute__((address_space(1))) unsigned int*)g,
        (__attribute__((address_space(3))) unsigned int*)l, 16, 0, 0);
}

// bijective chunked XCD swizzle (nwg % 8 == 0)
__device__ __forceinline__ int xcd_chunk(int bid, int nwg) {
    return (bid & 7) * (nwg >> 3) + (bid >> 3);
}

// ---------------- fused casts ----------------
__global__ __launch_bounds__(256) void cast_fused(const float* __restrict__ x,
                                                  const float* __restrict__ Wq, const float* __restrict__ Wk,
                                                  const float* __restrict__ Wv,
                                                  u16* __restrict__ xb, u16* __restrict__ Wqb,
                                                  u16* __restrict__ Wkb, u16* __restrict__ Wvt) {
    __shared__ float t[32][33];
    const int blk = blockIdx.x;
    if (blk < 5120) {
        const float* src; u16* dst; size_t i;
        if (blk < 4096)      { src = x;  dst = xb;  i = (size_t)blk * 2048; }
        else if (blk < 4608) { src = Wq; dst = Wqb; i = (size_t)(blk - 4096) * 2048; }
        else                 { src = Wk; dst = Wkb; i = (size_t)(blk - 4608) * 2048; }
        i += (size_t)threadIdx.x * 8;
        float4 a = *(const float4*)&src[i];
        float4 b = *(const float4*)&src[i + 4];
        short8 o;
        o[0]=f2bf(a.x); o[1]=f2bf(a.y); o[2]=f2bf(a.z); o[3]=f2bf(a.w);
        o[4]=f2bf(b.x); o[5]=f2bf(b.y); o[6]=f2bf(b.z); o[7]=f2bf(b.w);
        *(short8*)&dst[i] = o;
    } else {
        const int tb = blk - 5120;                 // 0..1023
        const int c = threadIdx.x & 31, r0 = threadIdx.x >> 5;
        const int i0 = (tb >> 5) * 32, j0 = (tb & 31) * 32;
#pragma unroll
        for (int rr = 0; rr < 4; ++rr)
            t[r0 + rr * 8][c] = Wv[(size_t)(i0 + r0 + rr * 8) * D_ + j0 + c];
        __syncthreads();
#pragma unroll
        for (int rr = 0; rr < 4; ++rr)
            Wvt[(size_t)(j0 + r0 + rr * 8) * D_ + i0 + c] = f2bf(t[c][r0 + rr * 8]);
    }
}

// =====================================================================================
// LDS layout (both cores): per buffer, per matrix, two k-half planes [kk][row][32].
// Within a row, 4 slots of 8 bf16; slot holds global k-octet (slot ^ ((row>>1)&3)).
// Swizzle applied on the GLOBAL source (gl_lds dest is linear) and on the ds_read addr
// (same involution) -> ds_read_b128 ~2-way bank aliasing (free).
// Chunk h = (kk<<2)|(mat<<1)|half; staged in consumption order; counted vmcnt confirms
// exactly the half-tile about to be read, never draining the prefetch stream to 0.
// =====================================================================================

// ================= 128x128 core: 4 waves, 2-phase (kk planes), counted vmcnt =========
__device__ __forceinline__ void mfma_nt_128(const u16* __restrict__ A, int lda,
                                            const u16* __restrict__ Bp, int ldb,
                                            int m0, int n0, int kext,
                                            u16* Sh, floatx4 acc[4][4])
{
    const int tid  = threadIdx.x;          // 0..255
    const int lane = tid & 63;
    const int lr   = lane & 15, quad = lane >> 4;
    const int wm   = ((tid >> 6) & 1) * 64, wn = (tid >> 7) * 64;
    const int nt   = kext >> 6;

    auto stage1 = [&](int t, int h) {      // 1 gl_lds / thread, 64 rows x 32 cols
        const int kk = h >> 2, mat = (h >> 1) & 1, half = h & 1;
        const int idx = tid * 8;           // 0..2047
        const int row = half * 64 + (idx >> 5);
        const int s   = (idx & 31) >> 3;
        const int gk  = (t << 6) + kk * 32 + ((s ^ ((row >> 1) & 3)) << 3);
        u16* dst = Sh + (t & 1) * 16384 + mat * 8192 + kk * 4096 + half * 2048 + idx;
        const u16* src = mat ? &Bp[(size_t)(n0 + row) * ldb + gk]
                             : &A [(size_t)(m0 + row) * lda + gk];
        gl_lds16(src, dst);
    };

#pragma unroll
    for (int h = 0; h < 8; ++h) stage1(0, h);              // prologue: tile 0

    for (int t = 0; t < nt; ++t) {
        const u16* buf = Sh + (t & 1) * 16384;
        const bool pf = (t + 1 < nt);
#pragma unroll
        for (int p = 0; p < 2; ++p) {                      // p = kk
            if (pf) {
#pragma unroll
                for (int h = 0; h < 4; ++h) stage1(t + 1, p * 4 + h);
                asm volatile("s_waitcnt vmcnt(8)" ::: "memory");   // drains tile t's kk=p planes
            } else if (p == 0) {
                asm volatile("s_waitcnt vmcnt(4)" ::: "memory");
            } else {
                asm volatile("s_waitcnt vmcnt(0)" ::: "memory");
            }
            __builtin_amdgcn_s_barrier();

            short8 af[4], bf[4];
#pragma unroll
            for (int i = 0; i < 4; ++i) {
                const int ar = wm + i * 16 + lr;
                af[i] = *(const short8*)&buf[p * 4096 + ar * 32 + ((quad ^ ((ar >> 1) & 3)) << 3)];
                const int br = wn + i * 16 + lr;
                bf[i] = *(const short8*)&buf[8192 + p * 4096 + br * 32 + ((quad ^ ((br >> 1) & 3)) << 3)];
            }
            asm volatile("s_waitcnt lgkmcnt(0)" ::: "memory");
            __builtin_amdgcn_s_setprio(1);
#pragma unroll
            for (int i = 0; i < 4; ++i)
#pragma unroll
                for (int j = 0; j < 4; ++j)
                    acc[i][j] = __builtin_amdgcn_mfma_f32_16x16x32_bf16(af[i], bf[j], acc[i][j], 0, 0, 0);
            __builtin_amdgcn_s_setprio(0);
            __builtin_amdgcn_s_barrier();
        }
    }
}

#define EPI_VARS                                              \
    const int lane = threadIdx.x & 63;                        \
    const int lr = lane & 15, quad = lane >> 4;               \
    const int wm = ((threadIdx.x >> 6) & 1) * 64, wn = (threadIdx.x >> 7) * 64;

// ================= 256x256 core: 8 waves (2Mx4N), 4-phase (kk x mh), counted vmcnt ====
__device__ __forceinline__ void mfma_nt_256(const u16* __restrict__ A, int lda,
                                            const u16* __restrict__ Bp, int ldb,
                                            int m0, int n0, int kext,
                                            u16* Sh, floatx4 acc[8][4])
{
    const int tid  = threadIdx.x;          // 0..511
    const int lane = tid & 63;
    const int lr   = lane & 15, quad = lane >> 4;
    const int wr   = (tid >> 8) & 1, wc = (tid >> 6) & 3;
    const int nt   = kext >> 6;

    auto stage1 = [&](int t, int h) {      // 1 gl_lds / thread, 128 rows x 32 cols
        const int kk = h >> 2, mat = (h >> 1) & 1, half = h & 1;
        const int idx = tid * 8;           // 0..4095
        const int row = half * 128 + (idx >> 5);
        const int s   = (idx & 31) >> 3;
        const int gk  = (t << 6) + kk * 32 + ((s ^ ((row >> 1) & 3)) << 3);
        u16* dst = Sh + (t & 1) * 32768 + mat * 16384 + kk * 8192 + half * 4096 + idx;
        const u16* src = mat ? &Bp[(size_t)(n0 + row) * ldb + gk]
                             : &A [(size_t)(m0 + row) * lda + gk];
        gl_lds16(src, dst);
    };

#pragma unroll
    for (int h = 0; h < 8; ++h) stage1(0, h);              // prologue: tile 0

    for (int t = 0; t < nt; ++t) {
        const u16* buf = Sh + (t & 1) * 32768;
        const bool pf = (t + 1 < nt);
        short8 af[4], bf[4];

        // ---- phase 0: (kk0, mh0) -- confirm tile t first half (A-pl0 + B-pl0)
        if (pf) { stage1(t + 1, 0); stage1(t + 1, 1);
                  asm volatile("s_waitcnt vmcnt(6)" ::: "memory"); }
        else      asm volatile("s_waitcnt vmcnt(4)" ::: "memory");
        __builtin_amdgcn_s_barrier();
#pragma unroll
        for (int i = 0; i < 4; ++i) {
            const int ar = wr * 128 + i * 16 + lr;
            af[i] = *(const short8*)&buf[ar * 32 + ((quad ^ ((ar >> 1) & 3)) << 3)];
            const int br = wc * 64 + i * 16 + lr;
            bf[i] = *(const short8*)&buf[16384 + br * 32 + ((quad ^ ((br >> 1) & 3)) << 3)];
        }
        asm volatile("s_waitcnt lgkmcnt(0)" ::: "memory");
        __builtin_amdgcn_s_setprio(1);
#pragma unroll
        for (int i = 0; i < 4; ++i)
#pragma unroll
            for (int j = 0; j < 4; ++j)
                acc[i][j] = __builtin_amdgcn_mfma_f32_16x16x32_bf16(af[i], bf[j], acc[i][j], 0, 0, 0);
        __builtin_amdgcn_s_setprio(0);
        __builtin_amdgcn_s_barrier();

        // ---- phase 1: (kk0, mh1) -- bf reused; reads early (data confirmed at p0)
#pragma unroll
        for (int i = 0; i < 4; ++i) {
            const int ar = wr * 128 + 64 + i * 16 + lr;
            af[i] = *(const short8*)&buf[ar * 32 + ((quad ^ ((ar >> 1) & 3)) << 3)];
        }
        if (pf) { stage1(t + 1, 2); stage1(t + 1, 3); }
        __builtin_amdgcn_s_barrier();
        asm volatile("s_waitcnt lgkmcnt(0)" ::: "memory");
        __builtin_amdgcn_s_setprio(1);
#pragma unroll
        for (int i = 0; i < 4; ++i)
#pragma unroll
            for (int j = 0; j < 4; ++j)
                acc[4 + i][j] = __builtin_amdgcn_mfma_f32_16x16x32_bf16(af[i], bf[j], acc[4 + i][j], 0, 0, 0);
        __builtin_amdgcn_s_setprio(0);
        __builtin_amdgcn_s_barrier();

        // ---- phase 2: (kk1, mh0) -- confirm tile t second half (A-pl1 + B-pl1)
        if (pf) { stage1(t + 1, 4); stage1(t + 1, 5);
                  asm volatile("s_waitcnt vmcnt(6)" ::: "memory"); }
        else      asm volatile("s_waitcnt vmcnt(0)" ::: "memory");
        __builtin_amdgcn_s_barrier();
#pragma unroll
        for (int i = 0; i < 4; ++i) {
            const int ar = wr * 128 + i * 16 + lr;
            af[i] = *(const short8*)&buf[8192 + ar * 32 + ((quad ^ ((ar >> 1) & 3)) << 3)];
            const int br = wc * 64 + i * 16 + lr;
            bf[i] = *(const short8*)&buf[24576 + br * 32 + ((quad ^ ((br >> 1) & 3)) << 3)];
        }
        asm volatile("s_waitcnt lgkmcnt(0)" ::: "memory");
        __builtin_amdgcn_s_setprio(1);
#pragma unroll
        for (int i = 0; i < 4; ++i)
#pragma unroll
            for (int j = 0; j < 4; ++j)
                acc[i][j] = __builtin_amdgcn_mfma_f32_16x16x32_bf16(af[i], bf[j], acc[i][j], 0, 0, 0);
        __builtin_amdgcn_s_setprio(0);
        __builtin_amdgcn_s_barrier();

        // ---- phase 3: (kk1, mh1)
#pragma unroll
        for (int i = 0; i < 4; ++i) {
            const int ar = wr * 128 + 64 + i * 16 + lr;
            af[i] = *(const short8*)&buf[8192 + ar * 32 + ((quad ^ ((ar >> 1) & 3)) << 3)];
        }
        if (pf) { stage1(t + 1, 6); stage1(t + 1, 7); }
        __builtin_amdgcn_s_barrier();
        asm volatile("s_waitcnt lgkmcnt(0)" ::: "memory");
        __builtin_amdgcn_s_setprio(1);
#pragma unroll
        for (int i = 0; i < 4; ++i)
#pragma unroll
            for (int j = 0; j < 4; ++j)
                acc[4 + i][j] = __builtin_amdgcn_mfma_f32_16x16x32_bf16(af[i], bf[j], acc[4 + i][j], 0, 0, 0);
        __builtin_amdgcn_s_setprio(0);
        __builtin_amdgcn_s_barrier();
    }
}

#define EPI256_VARS                                           \
    const int lane = threadIdx.x & 63;                        \
    const int lr = lane & 15, quad = lane >> 4;               \
    const int wr = (threadIdx.x >> 8) & 1, wc = (threadIdx.x >> 6) & 3;

// ---------------- K1: Mt = Wk *NT* Wq ----------------
__global__ __launch_bounds__(256) void mt_mfma(const u16* __restrict__ Wkb, const u16* __restrict__ Wqb,
                                               u16* __restrict__ Mt)
{
    __shared__ u16 Sh[32768];
    const int m0 = blockIdx.y * 128, n0 = blockIdx.x * 128;
    floatx4 acc[4][4];
#pragma unroll
    for (int i = 0; i < 4; ++i)
#pragma unroll
        for (int j = 0; j < 4; ++j) acc[i][j] = (floatx4){0.f, 0.f, 0.f, 0.f};
    mfma_nt_128(Wkb, D_, Wqb, D_, m0, n0, D_, Sh, acc);

    EPI_VARS
#pragma unroll
    for (int i = 0; i < 4; ++i)
#pragma unroll
        for (int j = 0; j < 4; ++j)
#pragma unroll
            for (int r = 0; r < 4; ++r)
                Mt[(size_t)(m0 + wm + i * 16 + quad * 4 + r) * D_ + n0 + wn + j * 16 + lr] = f2bf(acc[i][j][r]);
}

// ---------------- K2+K3 merged on 256^2 core: 256 blocks = 1/CU ----------------
__global__ __launch_bounds__(512, 2) void yv_mfma(const u16* __restrict__ xb, const u16* __restrict__ Mt,
                                                  const u16* __restrict__ Wvt,
                                                  u16* __restrict__ Y, u16* __restrict__ Vt)
{
    __shared__ u16 Sh[65536];                            // 128 KiB
    const int lid = xcd_chunk(blockIdx.x, 256);
    floatx4 acc[8][4];
#pragma unroll
    for (int i = 0; i < 8; ++i)
#pragma unroll
        for (int j = 0; j < 4; ++j) acc[i][j] = (floatx4){0.f, 0.f, 0.f, 0.f};

    if (lid < 128) {
        const int m0 = (lid >> 2) * 256, n0 = (lid & 3) * 256;
        mfma_nt_256(xb, D_, Mt, D_, m0, n0, D_, Sh, acc);
        EPI256_VARS
#pragma unroll
        for (int i = 0; i < 8; ++i)
#pragma unroll
            for (int j = 0; j < 4; ++j)
#pragma unroll
                for (int r = 0; r < 4; ++r)
                    Y[(size_t)(m0 + wr * 128 + i * 16 + quad * 4 + r) * D_ + n0 + wc * 64 + j * 16 + lr]
                        = f2bf(acc[i][j][r]);
    } else {
        const int v = lid - 128;
        const int b = v >> 5;
        const int mloc = ((v >> 2) & 7) * 256;
        const int n0 = (v & 3) * 256;
        const int m0 = b * S_ + mloc;
        u16* Vb = Vt + (size_t)b * D_ * S_;
        mfma_nt_256(xb, D_, Wvt, D_, m0, n0, D_, Sh, acc);
        EPI256_VARS
#pragma unroll
        for (int i = 0; i < 8; ++i)
#pragma unroll
            for (int j = 0; j < 4; ++j) {
                const int ee = n0 + wc * 64 + j * 16 + lr;
                const int s4 = mloc + wr * 128 + i * 16 + quad * 4;
                ushort4 o;
                o.x = f2bf(acc[i][j][0]); o.y = f2bf(acc[i][j][1]);
                o.z = f2bf(acc[i][j][2]); o.w = f2bf(acc[i][j][3]);
                *(ushort4*)&Vb[(size_t)ee * S_ + s4] = o;
            }
    }
}

// ---------------- K4: Sc = bf16(scale * Y x^T), 256-granular causal triangle ----------------
__global__ __launch_bounds__(512, 2) void scores_mfma(const u16* __restrict__ Y, const u16* __restrict__ xb,
                                                      u16* __restrict__ Sc)
{
    __shared__ u16 Sh[65536];
    const int lid = xcd_chunk(blockIdx.x, 144);
    const int b = lid / 36;
    const int t = lid - b * 36;
    int qt = 0;
    while ((qt + 1) * (qt + 2) / 2 <= t) ++qt;
    const int kt = t - qt * (qt + 1) / 2;

    const u16* A  = Y  + (size_t)b * S_ * D_;
    const u16* Bp = xb + (size_t)b * S_ * D_;
    u16* Sb = Sc + (size_t)b * S_ * S_;
    const int m0 = qt * 256, n0 = kt * 256;
    floatx4 acc[8][4];
#pragma unroll
    for (int i = 0; i < 8; ++i)
#pragma unroll
        for (int j = 0; j < 4; ++j) acc[i][j] = (floatx4){0.f, 0.f, 0.f, 0.f};
    mfma_nt_256(A, D_, Bp, D_, m0, n0, D_, Sh, acc);

    EPI256_VARS
#pragma unroll
    for (int i = 0; i < 8; ++i)
#pragma unroll
        for (int r = 0; r < 4; ++r) {
            const int grow = m0 + wr * 128 + i * 16 + quad * 4 + r;
#pragma unroll
            for (int j = 0; j < 4; ++j) {
                const int gcol = n0 + wc * 64 + j * 16 + lr;
                const float v = (gcol <= grow) ? acc[i][j][r] * SCALE : NEGINF;
                Sb[(size_t)grow * S_ + gcol] = f2bf(v);
            }
        }
}

// ---------------- K5: row softmax ----------------
__global__ __launch_bounds__(256) void softmax_k(const u16* __restrict__ Sc, u16* __restrict__ P)
{
    const int row = blockIdx.x;
    const int b = row >> 11, q = row & (S_ - 1);
    const int L = ((q >> 7) + 1) << 7;
    const u16* rp = Sc + ((size_t)b * S_ + q) * S_;
    u16* pp = P + ((size_t)b * S_ + q) * S_;
    __shared__ float red[4];
    __shared__ float bc;
    const int tid = threadIdx.x;
    const int i = tid << 3;
    const bool act = i < L;

    float f[8];
    float lmax = -3.4e38f;
    if (act) {
        short8 v = *(const short8*)&rp[i];
#pragma unroll
        for (int k = 0; k < 8; ++k) { f[k] = bf2f((u16)v[k]); lmax = fmaxf(lmax, f[k]); }
    }
    for (int off = 32; off; off >>= 1) lmax = fmaxf(lmax, __shfl_down(lmax, off, 64));
    if ((tid & 63) == 0) red[tid >> 6] = lmax;
    __syncthreads();
    if (tid == 0) bc = fmaxf(fmaxf(red[0], red[1]), fmaxf(red[2], red[3]));
    __syncthreads();
    const float m = bc;

    float lsum = 0.f;
    if (act) {
#pragma unroll
        for (int k = 0; k < 8; ++k) { f[k] = __expf(f[k] - m); lsum += f[k]; }
    }
    for (int off = 32; off; off >>= 1) lsum += __shfl_down(lsum, off, 64);
    if ((tid & 63) == 0) red[tid >> 6] = lsum;
    __syncthreads();
    if (tid == 0) bc = red[0] + red[1] + red[2] + red[3];
    __syncthreads();
    const float inv = 1.0f / bc;

    if (act) {
        short8 o;
#pragma unroll
        for (int k = 0; k < 8; ++k) o[k] = (short)f2bf(f[k] * inv);
        *(short8*)&pp[i] = o;
    }
}

// ---------------- K6: O = P Vt^T (causal K-extent), 128-core, et-major XCD chunks ----------------
__global__ __launch_bounds__(256) void pv_mfma(const u16* __restrict__ P, const u16* __restrict__ Vt,
                                               float* __restrict__ O)
{
    const int lid = xcd_chunk(blockIdx.x, 512);
    const int b  = lid >> 7;
    const int r  = lid & 127;
    const int et = r >> 4, qt = r & 15;
    __shared__ u16 Sh[32768];
    const u16* A  = P  + (size_t)b * S_ * S_;
    const u16* Bp = Vt + (size_t)b * D_ * S_;
    const int m0 = qt * 128, n0 = et * 128;
    const int kext = (qt + 1) * 128;
    floatx4 acc[4][4];
#pragma unroll
    for (int i = 0; i < 4; ++i)
#pragma unroll
        for (int j = 0; j < 4; ++j) acc[i][j] = (floatx4){0.f, 0.f, 0.f, 0.f};
    mfma_nt_128(A, S_, Bp, S_, m0, n0, kext, Sh, acc);

    EPI_VARS
#pragma unroll
    for (int i = 0; i < 4; ++i)
#pragma unroll
        for (int r2 = 0; r2 < 4; ++r2) {
            const int grow = m0 + wm + i * 16 + quad * 4 + r2;
#pragma unroll
            for (int j = 0; j < 4; ++j)
                O[((size_t)b * S_ + grow) * D_ + n0 + wn + j * 16 + lr] = acc[i][j][r2];
        }
}

extern "C" void kernel_launch(void* const* d_in, const int* in_sizes, int n_in,
                              void* d_out, int out_size, void* d_ws, size_t ws_size,
                              hipStream_t stream) {
    const float* x  = (const float*)d_in[0];
    const float* Wq = (const float*)d_in[1];
    const float* Wk = (const float*)d_in[2];
    const float* Wv = (const float*)d_in[3];
    float* out = (float*)d_out;
    char* w = (char*)d_ws;

    u16* xb  = (u16*)(w);                    // 16.8 MB
    u16* Wqb = (u16*)(w + 16777216);         //  2 MB
    u16* Wkb = (u16*)(w + 18874368);         //  2 MB
    u16* Wvt = (u16*)(w + 20971520);         //  2 MB
    u16* Mt  = (u16*)(w + 23068672);         //  2 MB
    u16* Y   = (u16*)(w + 25165824);         // 16.8 MB
    u16* Vt  = (u16*)(w + 41943040);         // 16.8 MB
    u16* Sc  = (u16*)(w + 58720256);         // 33.5 MB
    u16* P   = (u16*)(w + 92274688);         // 33.5 MB

    cast_fused <<<dim3(6144),   256, 0, stream>>>(x, Wq, Wk, Wv, xb, Wqb, Wkb, Wvt);
    mt_mfma    <<<dim3(8, 8),   256, 0, stream>>>(Wkb, Wqb, Mt);
    yv_mfma    <<<dim3(256),    512, 0, stream>>>(xb, Mt, Wvt, Y, Vt);
    scores_mfma<<<dim3(144),    512, 0, stream>>>(Y, xb, Sc);
    softmax_k  <<<dim3(N_),     256, 0, stream>>>(Sc, P);
    pv_mfma    <<<dim3(512),    256, 0, stream>>>(P, Vt, out);
}

// Round 4
// 208.123 us; speedup vs baseline: 1.2582x; 1.0883x over previous
//
#include <hip/hip_runtime.h>

#define B_  4
#define S_  2048
#define D_  1024
#define N_  (B_*S_)
#define SCALE 0.03125f
#define NEGINF (-3.0e38f)

typedef unsigned short u16;
typedef __attribute__((ext_vector_type(8))) short short8;
typedef __attribute__((ext_vector_type(4))) float floatx4;

__device__ __forceinline__ u16 f2bf(float f) {           // RNE float->bf16
    unsigned int u = __float_as_uint(f);
    u += 0x7FFFu + ((u >> 16) & 1u);
    return (u16)(u >> 16);
}
__device__ __forceinline__ float bf2f(u16 h) {
    return __uint_as_float((unsigned int)h << 16);
}

__device__ __forceinline__ void gl_lds16(const void* g, void* l) {
    __builtin_amdgcn_global_load_lds(
        (const __attribute__((address_space(1))) unsigned int*)g,
        (__attribute__((address_space(3))) unsigned int*)l, 16, 0, 0);
}

// bijective chunked XCD swizzle (nwg % 8 == 0)
__device__ __forceinline__ int xcd_chunk(int bid, int nwg) {
    return (bid & 7) * (nwg >> 3) + (bid >> 3);
}

// ---------------- fused casts ----------------
__global__ __launch_bounds__(256) void cast_fused(const float* __restrict__ x,
                                                  const float* __restrict__ Wq, const float* __restrict__ Wk,
                                                  const float* __restrict__ Wv,
                                                  u16* __restrict__ xb, u16* __restrict__ Wqb,
                                                  u16* __restrict__ Wkb, u16* __restrict__ Wvt) {
    __shared__ float t[32][33];
    const int blk = blockIdx.x;
    if (blk < 5120) {
        const float* src; u16* dst; size_t i;
        if (blk < 4096)      { src = x;  dst = xb;  i = (size_t)blk * 2048; }
        else if (blk < 4608) { src = Wq; dst = Wqb; i = (size_t)(blk - 4096) * 2048; }
        else                 { src = Wk; dst = Wkb; i = (size_t)(blk - 4608) * 2048; }
        i += (size_t)threadIdx.x * 8;
        float4 a = *(const float4*)&src[i];
        float4 b = *(const float4*)&src[i + 4];
        short8 o;
        o[0]=f2bf(a.x); o[1]=f2bf(a.y); o[2]=f2bf(a.z); o[3]=f2bf(a.w);
        o[4]=f2bf(b.x); o[5]=f2bf(b.y); o[6]=f2bf(b.z); o[7]=f2bf(b.w);
        *(short8*)&dst[i] = o;
    } else {
        const int tb = blk - 5120;                 // 0..1023
        const int c = threadIdx.x & 31, r0 = threadIdx.x >> 5;
        const int i0 = (tb >> 5) * 32, j0 = (tb & 31) * 32;
#pragma unroll
        for (int rr = 0; rr < 4; ++rr)
            t[r0 + rr * 8][c] = Wv[(size_t)(i0 + r0 + rr * 8) * D_ + j0 + c];
        __syncthreads();
#pragma unroll
        for (int rr = 0; rr < 4; ++rr)
            Wvt[(size_t)(j0 + r0 + rr * 8) * D_ + i0 + c] = f2bf(t[c][r0 + rr * 8]);
    }
}

// =====================================================================================
// LDS layout (all cores): per buffer, per matrix, two k-half planes [kk][row][32].
// Within a row, 4 slots of 8 bf16; slot holds global k-octet (slot ^ ((row>>1)&3)).
// Swizzle applied on the GLOBAL source (gl_lds dest is linear) and on the ds_read addr.
// Chunks staged in consumption order; counted vmcnt confirms exactly the half-tile
// about to be read, never draining the prefetch stream to 0 mid-loop.
// =====================================================================================

// ================= 128x128 core: 4 waves (256 thr), 2-phase, counted vmcnt =========
__device__ __forceinline__ void mfma_nt_128(const u16* __restrict__ A, int lda,
                                            const u16* __restrict__ Bp, int ldb,
                                            int m0, int n0, int kext,
                                            u16* Sh, floatx4 acc[4][4])
{
    const int tid  = threadIdx.x;          // 0..255
    const int lane = tid & 63;
    const int lr   = lane & 15, quad = lane >> 4;
    const int wm   = ((tid >> 6) & 1) * 64, wn = (tid >> 7) * 64;
    const int nt   = kext >> 6;

    auto stage1 = [&](int t, int h) {      // 1 gl_lds / thread, 64 rows x 32 cols
        const int kk = h >> 2, mat = (h >> 1) & 1, half = h & 1;
        const int idx = tid * 8;           // 0..2047
        const int row = half * 64 + (idx >> 5);
        const int s   = (idx & 31) >> 3;
        const int gk  = (t << 6) + kk * 32 + ((s ^ ((row >> 1) & 3)) << 3);
        u16* dst = Sh + (t & 1) * 16384 + mat * 8192 + kk * 4096 + half * 2048 + idx;
        const u16* src = mat ? &Bp[(size_t)(n0 + row) * ldb + gk]
                             : &A [(size_t)(m0 + row) * lda + gk];
        gl_lds16(src, dst);
    };

#pragma unroll
    for (int h = 0; h < 8; ++h) stage1(0, h);              // prologue: tile 0

    for (int t = 0; t < nt; ++t) {
        const u16* buf = Sh + (t & 1) * 16384;
        const bool pf = (t + 1 < nt);
#pragma unroll
        for (int p = 0; p < 2; ++p) {                      // p = kk
            if (pf) {
#pragma unroll
                for (int h = 0; h < 4; ++h) stage1(t + 1, p * 4 + h);
                asm volatile("s_waitcnt vmcnt(8)" ::: "memory");
            } else if (p == 0) {
                asm volatile("s_waitcnt vmcnt(4)" ::: "memory");
            } else {
                asm volatile("s_waitcnt vmcnt(0)" ::: "memory");
            }
            __builtin_amdgcn_s_barrier();

            short8 af[4], bf[4];
#pragma unroll
            for (int i = 0; i < 4; ++i) {
                const int ar = wm + i * 16 + lr;
                af[i] = *(const short8*)&buf[p * 4096 + ar * 32 + ((quad ^ ((ar >> 1) & 3)) << 3)];
                const int br = wn + i * 16 + lr;
                bf[i] = *(const short8*)&buf[8192 + p * 4096 + br * 32 + ((quad ^ ((br >> 1) & 3)) << 3)];
            }
            asm volatile("s_waitcnt lgkmcnt(0)" ::: "memory");
            __builtin_amdgcn_s_setprio(1);
#pragma unroll
            for (int i = 0; i < 4; ++i)
#pragma unroll
                for (int j = 0; j < 4; ++j)
                    acc[i][j] = __builtin_amdgcn_mfma_f32_16x16x32_bf16(af[i], bf[j], acc[i][j], 0, 0, 0);
            __builtin_amdgcn_s_setprio(0);
            __builtin_amdgcn_s_barrier();
        }
    }
}

#define EPI_VARS                                              \
    const int lane = threadIdx.x & 63;                        \
    const int lr = lane & 15, quad = lane >> 4;               \
    const int wm = ((threadIdx.x >> 6) & 1) * 64, wn = (threadIdx.x >> 7) * 64;

// ========== 128x128 core, 8 waves (512 thr): wave tile 32x64, 2-phase, counted vmcnt ====
// Same LDS layout/swizzle as mfma_nt_128; staging merged to 4 chunks/tile (512 thr cover
// a full 128x32 plane per chunk). Per phase: 6 ds_read_b128 + 8 MFMA per wave.
__device__ __forceinline__ void mfma_nt_128w8(const u16* __restrict__ A, int lda,
                                              const u16* __restrict__ Bp, int ldb,
                                              int m0, int n0, int kext,
                                              u16* Sh, floatx4 acc[2][4])
{
    const int tid  = threadIdx.x;          // 0..511
    const int lane = tid & 63;
    const int lr   = lane & 15, quad = lane >> 4;
    const int wid  = tid >> 6;             // 0..7
    const int wm   = (wid >> 1) * 32;      // 0,32,64,96
    const int wn   = (wid & 1) * 64;       // 0,64
    const int nt   = kext >> 6;

    auto stage1 = [&](int t, int h) {      // h = kk*2 + mat; 1 gl_lds / thread
        const int kk = h >> 1, mat = h & 1;
        const int idx = tid * 8;           // 0..4095 -> full 128x32 plane
        const int row = idx >> 5;
        const int s   = (idx & 31) >> 3;
        const int gk  = (t << 6) + kk * 32 + ((s ^ ((row >> 1) & 3)) << 3);
        u16* dst = Sh + (t & 1) * 16384 + mat * 8192 + kk * 4096 + idx;
        const u16* src = mat ? &Bp[(size_t)(n0 + row) * ldb + gk]
                             : &A [(size_t)(m0 + row) * lda + gk];
        gl_lds16(src, dst);
    };

#pragma unroll
    for (int h = 0; h < 4; ++h) stage1(0, h);              // prologue: tile 0

    for (int t = 0; t < nt; ++t) {
        const u16* buf = Sh + (t & 1) * 16384;
        const bool pf = (t + 1 < nt);
#pragma unroll
        for (int p = 0; p < 2; ++p) {                      // p = kk
            if (pf) {
                stage1(t + 1, p * 2); stage1(t + 1, p * 2 + 1);
                asm volatile("s_waitcnt vmcnt(4)" ::: "memory");   // t's kk=p planes done
            } else if (p == 0) {
                asm volatile("s_waitcnt vmcnt(2)" ::: "memory");
            } else {
                asm volatile("s_waitcnt vmcnt(0)" ::: "memory");
            }
            __builtin_amdgcn_s_barrier();

            short8 af[2], bf[4];
#pragma unroll
            for (int i = 0; i < 2; ++i) {
                const int ar = wm + i * 16 + lr;
                af[i] = *(const short8*)&buf[p * 4096 + ar * 32 + ((quad ^ ((ar >> 1) & 3)) << 3)];
            }
#pragma unroll
            for (int j = 0; j < 4; ++j) {
                const int br = wn + j * 16 + lr;
                bf[j] = *(const short8*)&buf[8192 + p * 4096 + br * 32 + ((quad ^ ((br >> 1) & 3)) << 3)];
            }
            asm volatile("s_waitcnt lgkmcnt(0)" ::: "memory");
            __builtin_amdgcn_s_setprio(1);
#pragma unroll
            for (int i = 0; i < 2; ++i)
#pragma unroll
                for (int j = 0; j < 4; ++j)
                    acc[i][j] = __builtin_amdgcn_mfma_f32_16x16x32_bf16(af[i], bf[j], acc[i][j], 0, 0, 0);
            __builtin_amdgcn_s_setprio(0);
            __builtin_amdgcn_s_barrier();
        }
    }
}

// ================= 256x256 core: 8 waves (2Mx4N), 4-phase (kk x mh), counted vmcnt ====
__device__ __forceinline__ void mfma_nt_256(const u16* __restrict__ A, int lda,
                                            const u16* __restrict__ Bp, int ldb,
                                            int m0, int n0, int kext,
                                            u16* Sh, floatx4 acc[8][4])
{
    const int tid  = threadIdx.x;          // 0..511
    const int lane = tid & 63;
    const int lr   = lane & 15, quad = lane >> 4;
    const int wr   = (tid >> 8) & 1, wc = (tid >> 6) & 3;
    const int nt   = kext >> 6;

    auto stage1 = [&](int t, int h) {      // 1 gl_lds / thread, 128 rows x 32 cols
        const int kk = h >> 2, mat = (h >> 1) & 1, half = h & 1;
        const int idx = tid * 8;           // 0..4095
        const int row = half * 128 + (idx >> 5);
        const int s   = (idx & 31) >> 3;
        const int gk  = (t << 6) + kk * 32 + ((s ^ ((row >> 1) & 3)) << 3);
        u16* dst = Sh + (t & 1) * 32768 + mat * 16384 + kk * 8192 + half * 4096 + idx;
        const u16* src = mat ? &Bp[(size_t)(n0 + row) * ldb + gk]
                             : &A [(size_t)(m0 + row) * lda + gk];
        gl_lds16(src, dst);
    };

#pragma unroll
    for (int h = 0; h < 8; ++h) stage1(0, h);              // prologue: tile 0

    for (int t = 0; t < nt; ++t) {
        const u16* buf = Sh + (t & 1) * 32768;
        const bool pf = (t + 1 < nt);
        short8 af[4], bf[4];

        // ---- phase 0: (kk0, mh0)
        if (pf) { stage1(t + 1, 0); stage1(t + 1, 1);
                  asm volatile("s_waitcnt vmcnt(6)" ::: "memory"); }
        else      asm volatile("s_waitcnt vmcnt(4)" ::: "memory");
        __builtin_amdgcn_s_barrier();
#pragma unroll
        for (int i = 0; i < 4; ++i) {
            const int ar = wr * 128 + i * 16 + lr;
            af[i] = *(const short8*)&buf[ar * 32 + ((quad ^ ((ar >> 1) & 3)) << 3)];
            const int br = wc * 64 + i * 16 + lr;
            bf[i] = *(const short8*)&buf[16384 + br * 32 + ((quad ^ ((br >> 1) & 3)) << 3)];
        }
        asm volatile("s_waitcnt lgkmcnt(0)" ::: "memory");
        __builtin_amdgcn_s_setprio(1);
#pragma unroll
        for (int i = 0; i < 4; ++i)
#pragma unroll
            for (int j = 0; j < 4; ++j)
                acc[i][j] = __builtin_amdgcn_mfma_f32_16x16x32_bf16(af[i], bf[j], acc[i][j], 0, 0, 0);
        __builtin_amdgcn_s_setprio(0);
        __builtin_amdgcn_s_barrier();

        // ---- phase 1: (kk0, mh1) -- bf reused
#pragma unroll
        for (int i = 0; i < 4; ++i) {
            const int ar = wr * 128 + 64 + i * 16 + lr;
            af[i] = *(const short8*)&buf[ar * 32 + ((quad ^ ((ar >> 1) & 3)) << 3)];
        }
        if (pf) { stage1(t + 1, 2); stage1(t + 1, 3); }
        __builtin_amdgcn_s_barrier();
        asm volatile("s_waitcnt lgkmcnt(0)" ::: "memory");
        __builtin_amdgcn_s_setprio(1);
#pragma unroll
        for (int i = 0; i < 4; ++i)
#pragma unroll
            for (int j = 0; j < 4; ++j)
                acc[4 + i][j] = __builtin_amdgcn_mfma_f32_16x16x32_bf16(af[i], bf[j], acc[4 + i][j], 0, 0, 0);
        __builtin_amdgcn_s_setprio(0);
        __builtin_amdgcn_s_barrier();

        // ---- phase 2: (kk1, mh0)
        if (pf) { stage1(t + 1, 4); stage1(t + 1, 5);
                  asm volatile("s_waitcnt vmcnt(6)" ::: "memory"); }
        else      asm volatile("s_waitcnt vmcnt(0)" ::: "memory");
        __builtin_amdgcn_s_barrier();
#pragma unroll
        for (int i = 0; i < 4; ++i) {
            const int ar = wr * 128 + i * 16 + lr;
            af[i] = *(const short8*)&buf[8192 + ar * 32 + ((quad ^ ((ar >> 1) & 3)) << 3)];
            const int br = wc * 64 + i * 16 + lr;
            bf[i] = *(const short8*)&buf[24576 + br * 32 + ((quad ^ ((br >> 1) & 3)) << 3)];
        }
        asm volatile("s_waitcnt lgkmcnt(0)" ::: "memory");
        __builtin_amdgcn_s_setprio(1);
#pragma unroll
        for (int i = 0; i < 4; ++i)
#pragma unroll
            for (int j = 0; j < 4; ++j)
                acc[i][j] = __builtin_amdgcn_mfma_f32_16x16x32_bf16(af[i], bf[j], acc[i][j], 0, 0, 0);
        __builtin_amdgcn_s_setprio(0);
        __builtin_amdgcn_s_barrier();

        // ---- phase 3: (kk1, mh1)
#pragma unroll
        for (int i = 0; i < 4; ++i) {
            const int ar = wr * 128 + 64 + i * 16 + lr;
            af[i] = *(const short8*)&buf[8192 + ar * 32 + ((quad ^ ((ar >> 1) & 3)) << 3)];
        }
        if (pf) { stage1(t + 1, 6); stage1(t + 1, 7); }
        __builtin_amdgcn_s_barrier();
        asm volatile("s_waitcnt lgkmcnt(0)" ::: "memory");
        __builtin_amdgcn_s_setprio(1);
#pragma unroll
        for (int i = 0; i < 4; ++i)
#pragma unroll
            for (int j = 0; j < 4; ++j)
                acc[4 + i][j] = __builtin_amdgcn_mfma_f32_16x16x32_bf16(af[i], bf[j], acc[4 + i][j], 0, 0, 0);
        __builtin_amdgcn_s_setprio(0);
        __builtin_amdgcn_s_barrier();
    }
}

#define EPI256_VARS                                           \
    const int lane = threadIdx.x & 63;                        \
    const int lr = lane & 15, quad = lane >> 4;               \
    const int wr = (threadIdx.x >> 8) & 1, wc = (threadIdx.x >> 6) & 3;

// ---------------- K1: Mt = Wk *NT* Wq ----------------
__global__ __launch_bounds__(256) void mt_mfma(const u16* __restrict__ Wkb, const u16* __restrict__ Wqb,
                                               u16* __restrict__ Mt)
{
    __shared__ u16 Sh[32768];
    const int m0 = blockIdx.y * 128, n0 = blockIdx.x * 128;
    floatx4 acc[4][4];
#pragma unroll
    for (int i = 0; i < 4; ++i)
#pragma unroll
        for (int j = 0; j < 4; ++j) acc[i][j] = (floatx4){0.f, 0.f, 0.f, 0.f};
    mfma_nt_128(Wkb, D_, Wqb, D_, m0, n0, D_, Sh, acc);

    EPI_VARS
#pragma unroll
    for (int i = 0; i < 4; ++i)
#pragma unroll
        for (int j = 0; j < 4; ++j)
#pragma unroll
            for (int r = 0; r < 4; ++r)
                Mt[(size_t)(m0 + wm + i * 16 + quad * 4 + r) * D_ + n0 + wn + j * 16 + lr] = f2bf(acc[i][j][r]);
}

// ---------------- K2+K3 merged on 256^2 core: 256 blocks = 1/CU ----------------
__global__ __launch_bounds__(512, 2) void yv_mfma(const u16* __restrict__ xb, const u16* __restrict__ Mt,
                                                  const u16* __restrict__ Wvt,
                                                  u16* __restrict__ Y, u16* __restrict__ Vt)
{
    __shared__ u16 Sh[65536];                            // 128 KiB
    const int lid = xcd_chunk(blockIdx.x, 256);
    floatx4 acc[8][4];
#pragma unroll
    for (int i = 0; i < 8; ++i)
#pragma unroll
        for (int j = 0; j < 4; ++j) acc[i][j] = (floatx4){0.f, 0.f, 0.f, 0.f};

    if (lid < 128) {
        const int m0 = (lid >> 2) * 256, n0 = (lid & 3) * 256;
        mfma_nt_256(xb, D_, Mt, D_, m0, n0, D_, Sh, acc);
        EPI256_VARS
#pragma unroll
        for (int i = 0; i < 8; ++i)
#pragma unroll
            for (int j = 0; j < 4; ++j)
#pragma unroll
                for (int r = 0; r < 4; ++r)
                    Y[(size_t)(m0 + wr * 128 + i * 16 + quad * 4 + r) * D_ + n0 + wc * 64 + j * 16 + lr]
                        = f2bf(acc[i][j][r]);
    } else {
        const int v = lid - 128;
        const int b = v >> 5;
        const int mloc = ((v >> 2) & 7) * 256;
        const int n0 = (v & 3) * 256;
        const int m0 = b * S_ + mloc;
        u16* Vb = Vt + (size_t)b * D_ * S_;
        mfma_nt_256(xb, D_, Wvt, D_, m0, n0, D_, Sh, acc);
        EPI256_VARS
#pragma unroll
        for (int i = 0; i < 8; ++i)
#pragma unroll
            for (int j = 0; j < 4; ++j) {
                const int ee = n0 + wc * 64 + j * 16 + lr;
                const int s4 = mloc + wr * 128 + i * 16 + quad * 4;
                ushort4 o;
                o.x = f2bf(acc[i][j][0]); o.y = f2bf(acc[i][j][1]);
                o.z = f2bf(acc[i][j][2]); o.w = f2bf(acc[i][j][3]);
                *(ushort4*)&Vb[(size_t)ee * S_ + s4] = o;
            }
    }
}

// ---------------- K4: Sc = bf16(scale * Y x^T), 256-granular causal triangle ----------------
__global__ __launch_bounds__(512, 2) void scores_mfma(const u16* __restrict__ Y, const u16* __restrict__ xb,
                                                      u16* __restrict__ Sc)
{
    __shared__ u16 Sh[65536];
    const int lid = xcd_chunk(blockIdx.x, 144);
    const int b = lid / 36;
    const int t = lid - b * 36;
    int qt = 0;
    while ((qt + 1) * (qt + 2) / 2 <= t) ++qt;
    const int kt = t - qt * (qt + 1) / 2;

    const u16* A  = Y  + (size_t)b * S_ * D_;
    const u16* Bp = xb + (size_t)b * S_ * D_;
    u16* Sb = Sc + (size_t)b * S_ * S_;
    const int m0 = qt * 256, n0 = kt * 256;
    floatx4 acc[8][4];
#pragma unroll
    for (int i = 0; i < 8; ++i)
#pragma unroll
        for (int j = 0; j < 4; ++j) acc[i][j] = (floatx4){0.f, 0.f, 0.f, 0.f};
    mfma_nt_256(A, D_, Bp, D_, m0, n0, D_, Sh, acc);

    EPI256_VARS
#pragma unroll
    for (int i = 0; i < 8; ++i)
#pragma unroll
        for (int r = 0; r < 4; ++r) {
            const int grow = m0 + wr * 128 + i * 16 + quad * 4 + r;
#pragma unroll
            for (int j = 0; j < 4; ++j) {
                const int gcol = n0 + wc * 64 + j * 16 + lr;
                const float v = (gcol <= grow) ? acc[i][j][r] * SCALE : NEGINF;
                Sb[(size_t)grow * S_ + gcol] = f2bf(v);
            }
        }
}

// ---------------- K5: row softmax, wave-per-row (no LDS, butterfly shfl) ----------------
__global__ __launch_bounds__(256) void softmax_k(const u16* __restrict__ Sc, u16* __restrict__ P)
{
    const int row = blockIdx.x * 4 + (threadIdx.x >> 6);
    const int lane = threadIdx.x & 63;
    const int b = row >> 11, q = row & (S_ - 1);
    const int L = ((q >> 7) + 1) << 7;           // 128-granular causal span (uniform per block)
    const u16* rp = Sc + ((size_t)b * S_ + q) * S_;
    u16* pp = P + ((size_t)b * S_ + q) * S_;

    float f[4][8];
    float lmax = -3.4e38f;
#pragma unroll
    for (int c = 0; c < 4; ++c) {
        const int i = c * 512 + lane * 8;
        if (i < L) {
            short8 v = *(const short8*)&rp[i];
#pragma unroll
            for (int k = 0; k < 8; ++k) { f[c][k] = bf2f((u16)v[k]); lmax = fmaxf(lmax, f[c][k]); }
        }
    }
#pragma unroll
    for (int off = 32; off; off >>= 1) lmax = fmaxf(lmax, __shfl_xor(lmax, off, 64));

    float lsum = 0.f;
#pragma unroll
    for (int c = 0; c < 4; ++c) {
        const int i = c * 512 + lane * 8;
        if (i < L) {
#pragma unroll
            for (int k = 0; k < 8; ++k) { f[c][k] = __expf(f[c][k] - lmax); lsum += f[c][k]; }
        }
    }
#pragma unroll
    for (int off = 32; off; off >>= 1) lsum += __shfl_xor(lsum, off, 64);
    const float inv = 1.0f / lsum;

#pragma unroll
    for (int c = 0; c < 4; ++c) {
        const int i = c * 512 + lane * 8;
        if (i < L) {
            short8 o;
#pragma unroll
            for (int k = 0; k < 8; ++k) o[k] = (short)f2bf(f[c][k] * inv);
            *(short8*)&pp[i] = o;
        }
    }
}

// ---------------- K6: O = P Vt^T, qt-paired (perfect balance: 17 K-tiles/block) ----------------
// 256 blocks (1/CU), 512 thr (8 waves). Block does qtA=pr and qtB=15-pr sequentially.
__device__ __forceinline__ void pv_epi(floatx4 acc[2][4], int b, int m0, int n0, float* __restrict__ O)
{
    const int lane = threadIdx.x & 63;
    const int lr = lane & 15, quad = lane >> 4;
    const int wid = threadIdx.x >> 6;
    const int wm = (wid >> 1) * 32, wn = (wid & 1) * 64;
#pragma unroll
    for (int i = 0; i < 2; ++i)
#pragma unroll
        for (int r = 0; r < 4; ++r) {
            const int grow = m0 + wm + i * 16 + quad * 4 + r;
#pragma unroll
            for (int j = 0; j < 4; ++j)
                O[((size_t)b * S_ + grow) * D_ + n0 + wn + j * 16 + lr] = acc[i][j][r];
        }
}

__global__ __launch_bounds__(512, 2) void pv_mfma(const u16* __restrict__ P, const u16* __restrict__ Vt,
                                                  float* __restrict__ O)
{
    __shared__ u16 Sh[32768];                  // 64 KiB: 2buf x (A 16KB + B 16KB)
    const int lid = xcd_chunk(blockIdx.x, 256);
    const int b  = lid >> 6;                   // 0..3
    const int et = (lid >> 3) & 7;             // 0..7
    const int pr = lid & 7;                    // 0..7
    const int n0 = et * 128;
    const u16* A  = P  + (size_t)b * S_ * S_;
    const u16* Bp = Vt + (size_t)b * D_ * S_;

    floatx4 acc[2][4];
    const int qtA = pr, qtB = 15 - pr;

#pragma unroll
    for (int i = 0; i < 2; ++i)
#pragma unroll
        for (int j = 0; j < 4; ++j) acc[i][j] = (floatx4){0.f, 0.f, 0.f, 0.f};
    mfma_nt_128w8(A, S_, Bp, S_, qtA * 128, n0, (qtA + 1) * 128, Sh, acc);
    pv_epi(acc, b, qtA * 128, n0, O);

#pragma unroll
    for (int i = 0; i < 2; ++i)
#pragma unroll
        for (int j = 0; j < 4; ++j) acc[i][j] = (floatx4){0.f, 0.f, 0.f, 0.f};
    mfma_nt_128w8(A, S_, Bp, S_, qtB * 128, n0, (qtB + 1) * 128, Sh, acc);
    pv_epi(acc, b, qtB * 128, n0, O);
}

extern "C" void kernel_launch(void* const* d_in, const int* in_sizes, int n_in,
                              void* d_out, int out_size, void* d_ws, size_t ws_size,
                              hipStream_t stream) {
    const float* x  = (const float*)d_in[0];
    const float* Wq = (const float*)d_in[1];
    const float* Wk = (const float*)d_in[2];
    const float* Wv = (const float*)d_in[3];
    float* out = (float*)d_out;
    char* w = (char*)d_ws;

    u16* xb  = (u16*)(w);                    // 16.8 MB
    u16* Wqb = (u16*)(w + 16777216);         //  2 MB
    u16* Wkb = (u16*)(w + 18874368);         //  2 MB
    u16* Wvt = (u16*)(w + 20971520);         //  2 MB
    u16* Mt  = (u16*)(w + 23068672);         //  2 MB
    u16* Y   = (u16*)(w + 25165824);         // 16.8 MB
    u16* Vt  = (u16*)(w + 41943040);         // 16.8 MB
    u16* Sc  = (u16*)(w + 58720256);         // 33.5 MB
    u16* P   = (u16*)(w + 92274688);         // 33.5 MB

    cast_fused <<<dim3(6144),   256, 0, stream>>>(x, Wq, Wk, Wv, xb, Wqb, Wkb, Wvt);
    mt_mfma    <<<dim3(8, 8),   256, 0, stream>>>(Wkb, Wqb, Mt);
    yv_mfma    <<<dim3(256),    512, 0, stream>>>(xb, Mt, Wvt, Y, Vt);
    scores_mfma<<<dim3(144),    512, 0, stream>>>(Y, xb, Sc);
    softmax_k  <<<dim3(N_/4),   256, 0, stream>>>(Sc, P);
    pv_mfma    <<<dim3(256),    512, 0, stream>>>(P, Vt, out);
}